// Round 1
// 726.454 us; speedup vs baseline: 1.1177x; 1.1177x over previous
//
#include <hip/hip_runtime.h>
#include <math.h>

typedef float    f32x4 __attribute__((ext_vector_type(4)));
typedef _Float16 f16x8 __attribute__((ext_vector_type(8)));
typedef _Float16 f16x4 __attribute__((ext_vector_type(4)));

#define M_TOKENS 32768
#define D_MODEL  4096
#define N_EXPERTS 64

constexpr int BT = 64;                      // tokens per block
constexpr int BK = 64;                      // k per chunk
constexpr int NCHUNK = D_MODEL / BK;        // 64
constexpr int PLANE  = N_EXPERTS * BK * 2;  // 8192 B per split plane per chunk
constexpr int CHUNK_BYTES = 2 * PLANE;      // 16384 B (hi+lo planes)
constexpr float RS   = 2048.0f;             // residual scale 2^11 (keeps lo out of fp16 subnormals)
constexpr float IRS  = 1.0f / 2048.0f;
constexpr float WSC  = 64.0f;               // W pre-scale (keeps wh out of fp16 subnormals)
constexpr float IWSC = 1.0f / 64.0f;

// ---- pass 1: W (64x4096 fp32) -> fp16x2 planes, chunk-contiguous, pre-swizzled ----
// Layout: chunk c holds 16384 B: [hi plane 8192 B][lo plane 8192 B].
// Within a plane, expert e row = 128 B; byte offset (e*128 + kq*2) ^ ((e&7)<<4).
// The XOR stays within 16B-granule resolution (bits 4-6), so 16B stores/loads are safe.
__global__ __launch_bounds__(256)
void split_w_kernel(const float* __restrict__ W, unsigned char* __restrict__ Wsp)
{
    const int t = blockIdx.x * 256 + threadIdx.x;   // 32768 threads, 8 k-elems each
    const int e = t >> 9;                           // 512 granules per expert
    const int g = t & 511;
    const int c = g >> 3;                           // chunk 0..63
    const int q = g & 7;                            // 16B granule within chunk row
    const float* src = W + ((size_t)e << 12) + (c << 6) + (q << 3);
    const float4 v0 = *reinterpret_cast<const float4*>(src);
    const float4 v1 = *reinterpret_cast<const float4*>(src + 4);
    const float vv[8] = {v0.x, v0.y, v0.z, v0.w, v1.x, v1.y, v1.z, v1.w};
    f16x8 hv, lv;
#pragma unroll
    for (int j = 0; j < 8; ++j) {
        const float s = vv[j] * WSC;                // exact (pow2)
        const _Float16 h = (_Float16)s;             // RNE
        const float r = (s - (float)h) * RS;        // exact residual, exact pow2 scale
        hv[j] = h;
        lv[j] = (_Float16)r;
    }
    const int lin = e * 128 + q * 16;
    const int sw  = lin ^ ((e & 7) << 4);
    unsigned char* dst = Wsp + (size_t)c * CHUNK_BYTES + sw;
    *reinterpret_cast<f16x8*>(dst)         = hv;
    *reinterpret_cast<f16x8*>(dst + PLANE) = lv;
}

// ---- pass 2: fused fp16x2 MFMA GEMM + top-2 + softmax ----
// 256 threads = 4 waves, 2x2 wave grid: wave owns 32 tokens x 32 experts.
// LDS 32 KB -> 2 blocks/CU, 2 waves/SIMD. 1-deep register prefetch of next chunk.
__global__ __launch_bounds__(256, 2)
void router_mfma_kernel(const float* __restrict__ X,
                        const unsigned char* __restrict__ Wsp,
                        const float* __restrict__ b,
                        float* __restrict__ out)
{
    __shared__ __align__(16) unsigned char SMEM[2 * CHUNK_BYTES];   // 32768 B
    unsigned char* Xs = SMEM;                    // X tile: hi[0,8192) lo[8192,16384)
    unsigned char* Ws = SMEM + CHUNK_BYTES;      // W tile: hi/lo planes

    const int tid  = threadIdx.x;
    const int wv   = tid >> 6;
    const int lane = tid & 63;
    const int l15  = lane & 15;
    const int quad = lane >> 4;
    const int wr   = (wv >> 1) * 32;             // wave token base
    const int wc   = (wv & 1) * 32;              // wave expert base
    const int t0   = blockIdx.x * BT;

    f32x4 a1[2][2], a2[2][2];
#pragma unroll
    for (int tt = 0; tt < 2; ++tt)
#pragma unroll
        for (int et = 0; et < 2; ++et) {
            a1[tt][et] = (f32x4){0.f, 0.f, 0.f, 0.f};
            a2[tt][et] = (f32x4){0.f, 0.f, 0.f, 0.f};
        }

    // staging geometry: thread covers rows {i*16 + tid>>4}, k-granule (tid&15)*4
    const int srow = tid >> 4;
    const int scol = tid & 15;
    const float* xptr = X + (size_t)(t0 + srow) * D_MODEL + (scol << 2);
    const unsigned char* wptr = Wsp + tid * 16;

    float4 xr[4];
    f16x8  wrg[4];
#pragma unroll
    for (int i = 0; i < 4; ++i) {                       // prologue: chunk 0
        xr[i]  = *reinterpret_cast<const float4*>(xptr + (size_t)i * 16 * D_MODEL);
        wrg[i] = *reinterpret_cast<const f16x8*>(wptr + i * 4096);
    }

    for (int c = 0; c < NCHUNK; ++c) {
        if (c) __syncthreads();                         // prior readers done

        // ---- split + stage X (xr waits vmcnt while wrg still in flight) ----
#pragma unroll
        for (int i = 0; i < 4; ++i) {
            const float vv[4] = {xr[i].x, xr[i].y, xr[i].z, xr[i].w};
            f16x4 hv, lv;
#pragma unroll
            for (int j = 0; j < 4; ++j) {
                const _Float16 h = (_Float16)vv[j];
                hv[j] = h;
                lv[j] = (_Float16)((vv[j] - (float)h) * RS);
            }
            const int row = i * 16 + srow;
            const int sw  = (row * 128 + (scol << 3)) ^ ((row & 7) << 4);
            *reinterpret_cast<f16x4*>(Xs + sw)         = hv;
            *reinterpret_cast<f16x4*>(Xs + PLANE + sw) = lv;
        }
        // ---- stage W: pure linear copy (swizzle pre-baked in Wsp) ----
#pragma unroll
        for (int i = 0; i < 4; ++i)
            *reinterpret_cast<f16x8*>(Ws + i * 4096 + tid * 16) = wrg[i];

        __syncthreads();                                // no outstanding vmem here

        // ---- prefetch next chunk (in flight under compute) ----
        if (c + 1 < NCHUNK) {
            const float* xp = xptr + (c + 1) * BK;
            const unsigned char* wp = wptr + (size_t)(c + 1) * CHUNK_BYTES;
#pragma unroll
            for (int i = 0; i < 4; ++i) {
                xr[i]  = *reinterpret_cast<const float4*>(xp + (size_t)i * 16 * D_MODEL);
                wrg[i] = *reinterpret_cast<const f16x8*>(wp + i * 4096);
            }
        }

        // ---- compute: 2 ksteps x (2x2 tiles) x 3 MFMA ----
#pragma unroll
        for (int ks = 0; ks < 2; ++ks) {
            f16x8 ah[2], al[2], bh[2], bl[2];
#pragma unroll
            for (int tt = 0; tt < 2; ++tt) {
                const int row = wr + tt * 16 + l15;
                const int sw  = (row * 128 + ks * 64 + quad * 16) ^ ((row & 7) << 4);
                ah[tt] = *reinterpret_cast<const f16x8*>(Xs + sw);
                al[tt] = *reinterpret_cast<const f16x8*>(Xs + PLANE + sw);
            }
#pragma unroll
            for (int et = 0; et < 2; ++et) {
                const int erow = wc + et * 16 + l15;
                const int sw   = (erow * 128 + ks * 64 + quad * 16) ^ ((erow & 7) << 4);
                bh[et] = *reinterpret_cast<const f16x8*>(Ws + sw);
                bl[et] = *reinterpret_cast<const f16x8*>(Ws + PLANE + sw);
            }
#pragma unroll
            for (int tt = 0; tt < 2; ++tt)
#pragma unroll
                for (int et = 0; et < 2; ++et) {
                    a1[tt][et] = __builtin_amdgcn_mfma_f32_16x16x32_f16(ah[tt], bh[et], a1[tt][et], 0, 0, 0);
                    a2[tt][et] = __builtin_amdgcn_mfma_f32_16x16x32_f16(ah[tt], bl[et], a2[tt][et], 0, 0, 0);
                    a2[tt][et] = __builtin_amdgcn_mfma_f32_16x16x32_f16(al[tt], bh[et], a2[tt][et], 0, 0, 0);
                }
        }
    }

    // ---- epilogue: scores -> LDS, top-2 + softmax ----
    __syncthreads();
    float* Ss = reinterpret_cast<float*>(SMEM);         // 64*65*4 = 16640 B <= 32768
#pragma unroll
    for (int tt = 0; tt < 2; ++tt)
#pragma unroll
        for (int et = 0; et < 2; ++et)
#pragma unroll
            for (int r = 0; r < 4; ++r) {
                const int tok = wr + tt * 16 + quad * 4 + r;   // C/D: row=(lane>>4)*4+reg
                const int e   = wc + et * 16 + l15;            //      col=lane&15
                Ss[tok * 65 + e] = (a1[tt][et][r] + a2[tt][et][r] * IRS) * IWSC;
            }
    __syncthreads();

    if (tid < BT) {
        const int t = tid;
        float best = -INFINITY, second = -INFINITY;
        int bi = 0, si = 0;
        for (int e = 0; e < N_EXPERTS; ++e) {
            const float s = Ss[t * 65 + e] + b[e];
            if (s > best) {
                second = best; si = bi;
                best = s;      bi = e;
            } else if (s > second) {
                second = s;    si = e;
            }
        }
        const float e2  = expf(second - best);
        const float inv = 1.0f / (1.0f + e2);

        const size_t tg = (size_t)(t0 + t);
        out[tg * 2 + 0] = inv;
        out[tg * 2 + 1] = e2 * inv;
        float* idx_out = out + (size_t)M_TOKENS * 2;
        idx_out[tg * 2 + 0] = (float)bi;
        idx_out[tg * 2 + 1] = (float)si;
    }
}

extern "C" void kernel_launch(void* const* d_in, const int* in_sizes, int n_in,
                              void* d_out, int out_size, void* d_ws, size_t ws_size,
                              hipStream_t stream) {
    const float* X = (const float*)d_in[0];
    const float* W = (const float*)d_in[1];
    const float* b = (const float*)d_in[2];
    float* out = (float*)d_out;
    unsigned char* Wsp = (unsigned char*)d_ws;          // needs 64*16384 = 1 MB

    hipLaunchKernelGGL(split_w_kernel, dim3((N_EXPERTS * D_MODEL) / (256 * 8)), dim3(256), 0, stream,
                       W, Wsp);
    hipLaunchKernelGGL(router_mfma_kernel, dim3(M_TOKENS / BT), dim3(256), 0, stream,
                       X, Wsp, b, out);
}